// Round 3
// baseline (943.516 us; speedup 1.0000x reference)
//
#include <hip/hip_runtime.h>
#include <hip/hip_bf16.h>
#include <stdint.h>

// Problem dims (hardcoded from reference):
// B=256, T=100, D=2*34*34=2312, H=1000, O=10.  ALL tensors fp32.
#define T_STEPS 100
#define B_SZ    256
#define D_IN    2312
#define H_SZ    1000
#define O_SZ    10
#define M_ROWS  (B_SZ * T_STEPS)   // 25600
#define K_PAD   2336               // 73 * 32 (W pre-split padded)
#define KT      73
#define W_ROWS  1024               // H padded to 1024 rows (rows >= 1000 zeroed)

// fp16 split scaling keeps lo-parts out of f16 subnormals.
// A*16 (|a|<6), W*64 (|w|<0.022).  Epilogue scale = 1/1024 (exact pow2).
#define A_SCALE   16.0f
#define W_SCALE   64.0f
#define INV_SCALE (1.0f / 1024.0f)

typedef __attribute__((ext_vector_type(4))) float     floatx4;
typedef __attribute__((ext_vector_type(8))) _Float16  halfx8;

#define ASYNC_COPY16(g, l)                                             \
  __builtin_amdgcn_global_load_lds(                                    \
      (const __attribute__((address_space(1))) void*)(g),              \
      (__attribute__((address_space(3))) void*)(l), 16, 0, 0)

// ---------------------------------------------------------------------------
// W pre-split: fp32 -> f16 hi/lo, scaled by 64, rows padded to K_PAD/W_ROWS.
// ---------------------------------------------------------------------------
__global__ __launch_bounds__(256)
void splitW_kernel(const float* __restrict__ W,    // [H_SZ, D_IN]
                   _Float16* __restrict__ wHi,     // [W_ROWS, K_PAD]
                   _Float16* __restrict__ wLo)
{
  const int r = blockIdx.x;
  const bool rvalid = (r < H_SZ);
  const float* w = W + (size_t)(rvalid ? r : 0) * D_IN;
  _Float16* ho = wHi + (size_t)r * K_PAD;
  _Float16* lo = wLo + (size_t)r * K_PAD;
  for (int c = threadIdx.x; c < K_PAD / 8; c += 256) {
    const int k0 = c * 8;
    const bool v = rvalid && (k0 + 8 <= D_IN);
    _Float16 h[8], l[8];
    #pragma unroll
    for (int e = 0; e < 8; ++e) {
      const float x = v ? w[k0 + e] * W_SCALE : 0.f;
      const _Float16 hb = (_Float16)x;
      h[e] = hb;
      l[e] = (_Float16)(x - (float)hb);
    }
    *reinterpret_cast<uint4*>(ho + k0) = *reinterpret_cast<const uint4*>(h);
    *reinterpret_cast<uint4*>(lo + k0) = *reinterpret_cast<const uint4*>(l);
  }
}

// ---------------------------------------------------------------------------
// Phase 1 (fused): cur1 = (A*16 fp32->f16split @ Wsplit) / 1024 + b1.
// 128x128 tile, BK=32, 4 waves 64x64, 3-pass split-f16 MFMA.
//
// Round-8: counted-vmcnt pipeline on the round-7 full double-buffer.
// Invariant at loop top (steady state): outstanding vmem =
//   [ W-DMA(kt) : oldest 4 ][ A-loads(kt+1) : newest 4 ]
// s_waitcnt vmcnt(4) retires exactly W(kt) (which filled the buffer this
// iter reads) and keeps A(kt+1) in flight; this iter's W(kt+1)/A(kt+2)
// stay outstanding across the NEXT barrier (T4 mechanism: never drain to
// 0 in the main loop).  Issue order inside the iter (split -> W-DMA ->
// A-load) is what makes the counts line up.  sched_barrier(0) fences the
// asm per guide rule #18.  T5 setprio wraps the MFMA cluster (waves now
// have role diversity across the pipelined phases).
// Numerics bit-identical (same MFMA order): absmax must stay 0.03125.
// ---------------------------------------------------------------------------
__global__ __launch_bounds__(256)
void gemm1_fused(const float* __restrict__ A,       // [M_ROWS, D_IN] fp32
                 const _Float16* __restrict__ wHi,  // [W_ROWS, K_PAD]
                 const _Float16* __restrict__ wLo,
                 const float* __restrict__ b1,      // [H_SZ]
                 float* __restrict__ C)             // [M_ROWS, H_SZ]
{
  __shared__ _Float16 sAh[2][128 * 32];
  __shared__ _Float16 sAl[2][128 * 32];
  __shared__ _Float16 sBh[2][128 * 32];
  __shared__ _Float16 sBl[2][128 * 32];   // 64 KB total -> 2 blocks/CU

  const int tid  = threadIdx.x;

  // XCD-aware remap (bijective: 1600 = 8 XCDs x 200).
  const int id  = blockIdx.x;            // 0..1599, XCD = id & 7
  const int j   = id >> 3;               // 0..199
  const int mt  = (id & 7) * 25 + (j >> 3);
  const int nt  = j & 7;
  const int m0  = mt * 128;
  const int n0  = nt * 128;

  const int wid  = tid >> 6;
  const int lane = tid & 63;
  const int wm   = (wid & 1) * 64;
  const int wn   = (wid >> 1) * 64;
  const int quad = lane >> 4;
  const int l16  = lane & 15;

  floatx4 acc[4][4];
  #pragma unroll
  for (int i = 0; i < 4; ++i)
    #pragma unroll
    for (int jj = 0; jj < 4; ++jj)
      acc[i][jj] = floatx4{0.f, 0.f, 0.f, 0.f};

  // Staging map: thread tid owns rows r0=tid>>2 and r1=r0+64, LDS slot tid&3.
  // Swizzle: slot s of row r holds global chunk s ^ rho(r), rho(r)=(r>>1)&3.
  const int r0  = tid >> 2;
  const int r1  = r0 + 64;
  const int sl  = tid & 3;
  const int rho = (r0 >> 1) & 3;
  const int ko  = ((sl ^ rho) * 8);   // swizzled global chunk offset (elements)

  const float* gA0 = A + (size_t)(m0 + r0) * D_IN + ko;
  const float* gA1 = A + (size_t)(m0 + r1) * D_IN + ko;
  const _Float16* gBh0 = wHi + (size_t)(n0 + r0) * K_PAD + ko;
  const _Float16* gBh1 = wHi + (size_t)(n0 + r1) * K_PAD + ko;
  const _Float16* gBl0 = wLo + (size_t)(n0 + r0) * K_PAD + ko;
  const _Float16* gBl1 = wLo + (size_t)(n0 + r1) * K_PAD + ko;

  const int la0 = tid * 8;          // per-buffer LDS element offsets
  const int la1 = (tid + 256) * 8;

  // Fragment-read swizzle offset (elements).
  const int fo = (quad ^ ((l16 >> 1) & 3)) * 8;

  // ---- Prologue.  Issue A(0) FIRST (so it retires first), then W(0) DMA.
  float a0[8], a1[8];
  *reinterpret_cast<float4*>(a0)     = *reinterpret_cast<const float4*>(gA0);
  *reinterpret_cast<float4*>(a0 + 4) = *reinterpret_cast<const float4*>(gA0 + 4);
  *reinterpret_cast<float4*>(a1)     = *reinterpret_cast<const float4*>(gA1);
  *reinterpret_cast<float4*>(a1 + 4) = *reinterpret_cast<const float4*>(gA1 + 4);

  ASYNC_COPY16(gBh0, &sBh[0][la0]);
  ASYNC_COPY16(gBh1, &sBh[0][la1]);
  ASYNC_COPY16(gBl0, &sBl[0][la0]);
  ASYNC_COPY16(gBl1, &sBl[0][la1]);

  // Split A(0) -> sA[0] (compiler waits A(0) = oldest 4 -> vmcnt(4),
  // leaving the W(0) DMAs in flight).
  {
    _Float16 h0[8], l0[8], h1[8], l1[8];
    #pragma unroll
    for (int e = 0; e < 8; ++e) {
      const float v0 = a0[e] * A_SCALE;
      const _Float16 hb0 = (_Float16)v0;
      h0[e] = hb0; l0[e] = (_Float16)(v0 - (float)hb0);
      const float v1 = a1[e] * A_SCALE;
      const _Float16 hb1 = (_Float16)v1;
      h1[e] = hb1; l1[e] = (_Float16)(v1 - (float)hb1);
    }
    *reinterpret_cast<uint4*>(&sAh[0][la0]) = *reinterpret_cast<const uint4*>(h0);
    *reinterpret_cast<uint4*>(&sAl[0][la0]) = *reinterpret_cast<const uint4*>(l0);
    *reinterpret_cast<uint4*>(&sAh[0][la1]) = *reinterpret_cast<const uint4*>(h1);
    *reinterpret_cast<uint4*>(&sAl[0][la1]) = *reinterpret_cast<const uint4*>(l1);
  }

  // A(1) into registers (in-bounds: 32 + ko + 8 <= 64 < D_IN).
  *reinterpret_cast<float4*>(a0)     = *reinterpret_cast<const float4*>(gA0 + 32);
  *reinterpret_cast<float4*>(a0 + 4) = *reinterpret_cast<const float4*>(gA0 + 36);
  *reinterpret_cast<float4*>(a1)     = *reinterpret_cast<const float4*>(gA1 + 32);
  *reinterpret_cast<float4*>(a1 + 4) = *reinterpret_cast<const float4*>(gA1 + 36);
  bool curValid = true;
  // Entering loop: outstanding = [W(0) x4 older][A(1) x4 newer].

  for (int kt = 0; kt < KT; ++kt) {
    const int p = kt & 1;

    // Counted barrier: retire W(kt) (fills [p]); keep A(kt+1) in flight.
    asm volatile("s_waitcnt vmcnt(4) lgkmcnt(0)" ::: "memory");
    __builtin_amdgcn_sched_barrier(0);
    __builtin_amdgcn_s_barrier();
    __builtin_amdgcn_sched_barrier(0);

    // ---- (1) fragment reads of tile kt from [p].
    halfx8 ah[4], bh[4], al[4], bl[4];
    #pragma unroll
    for (int i = 0; i < 4; ++i) {
      const int row = (wm + i * 16 + l16) * 32 + fo;
      ah[i] = *reinterpret_cast<const halfx8*>(&sAh[p][row]);
      al[i] = *reinterpret_cast<const halfx8*>(&sAl[p][row]);
    }
    #pragma unroll
    for (int jj = 0; jj < 4; ++jj) {
      const int row = (wn + jj * 16 + l16) * 32 + fo;
      bh[jj] = *reinterpret_cast<const halfx8*>(&sBh[p][row]);
      bl[jj] = *reinterpret_cast<const halfx8*>(&sBl[p][row]);
    }

    // ---- (2) stage tile kt+1 into [p^1]: split A(kt+1) regs -> ds_write,
    // then W-DMA(kt+1), then A-load(kt+2).  This issue order maintains the
    // loop-top invariant.
    if (kt + 1 < KT) {
      _Float16 h0[8], l0[8], h1[8], l1[8];
      #pragma unroll
      for (int e = 0; e < 8; ++e) {
        const float v0 = curValid ? a0[e] * A_SCALE : 0.f;
        const _Float16 hb0 = (_Float16)v0;
        h0[e] = hb0; l0[e] = (_Float16)(v0 - (float)hb0);
        const float v1 = curValid ? a1[e] * A_SCALE : 0.f;
        const _Float16 hb1 = (_Float16)v1;
        h1[e] = hb1; l1[e] = (_Float16)(v1 - (float)hb1);
      }
      const int q = p ^ 1;
      *reinterpret_cast<uint4*>(&sAh[q][la0]) = *reinterpret_cast<const uint4*>(h0);
      *reinterpret_cast<uint4*>(&sAl[q][la0]) = *reinterpret_cast<const uint4*>(l0);
      *reinterpret_cast<uint4*>(&sAh[q][la1]) = *reinterpret_cast<const uint4*>(h1);
      *reinterpret_cast<uint4*>(&sAl[q][la1]) = *reinterpret_cast<const uint4*>(l1);

      const int kb = (kt + 1) * 32;
      ASYNC_COPY16(gBh0 + kb, &sBh[q][la0]);
      ASYNC_COPY16(gBh1 + kb, &sBh[q][la1]);
      ASYNC_COPY16(gBl0 + kb, &sBl[q][la0]);
      ASYNC_COPY16(gBl1 + kb, &sBl[q][la1]);

      // A(kt+2) regs -- ALWAYS issued (clamped) to keep the vmcnt invariant.
      const int kb2 = (kt + 2) * 32;
      const bool v = (kb2 + ko) < D_IN;      // chunk fully valid (D_IN%8==0)
      const int off = v ? kb2 : 0;
      *reinterpret_cast<float4*>(a0)     = *reinterpret_cast<const float4*>(gA0 + off);
      *reinterpret_cast<float4*>(a0 + 4) = *reinterpret_cast<const float4*>(gA0 + off + 4);
      *reinterpret_cast<float4*>(a1)     = *reinterpret_cast<const float4*>(gA1 + off);
      *reinterpret_cast<float4*>(a1 + 4) = *reinterpret_cast<const float4*>(gA1 + off + 4);
      curValid = v;
    }

    // ---- (3) 48 MFMA on tile kt (same order: hh, lh, hl).
    __builtin_amdgcn_s_setprio(1);
    #pragma unroll
    for (int i = 0; i < 4; ++i)
      #pragma unroll
      for (int jj = 0; jj < 4; ++jj)
        acc[i][jj] = __builtin_amdgcn_mfma_f32_16x16x32_f16(ah[i], bh[jj], acc[i][jj], 0, 0, 0);
    #pragma unroll
    for (int i = 0; i < 4; ++i)
      #pragma unroll
      for (int jj = 0; jj < 4; ++jj)
        acc[i][jj] = __builtin_amdgcn_mfma_f32_16x16x32_f16(al[i], bh[jj], acc[i][jj], 0, 0, 0);
    #pragma unroll
    for (int i = 0; i < 4; ++i)
      #pragma unroll
      for (int jj = 0; jj < 4; ++jj)
        acc[i][jj] = __builtin_amdgcn_mfma_f32_16x16x32_f16(ah[i], bl[jj], acc[i][jj], 0, 0, 0);
    __builtin_amdgcn_s_setprio(0);
  }

  // Epilogue: C/D layout col = lane&15, row = quad*4 + reg (m89/m91 verified).
  #pragma unroll
  for (int jj = 0; jj < 4; ++jj) {
    const int col = n0 + wn + jj * 16 + l16;
    if (col < H_SZ) {
      const float bias = b1[col];
      #pragma unroll
      for (int i = 0; i < 4; ++i) {
        const int row = m0 + wm + i * 16 + quad * 4;
        #pragma unroll
        for (int r = 0; r < 4; ++r)
          C[(size_t)(row + r) * H_SZ + col] = acc[i][jj][r] * INV_SCALE + bias;
      }
    }
  }
}

// ---------------------------------------------------------------------------
// Phase 2 (fused): layer-1 LIF scan + layer-2 GEMM in one kernel.
// One block per batch element b; thread tid owns 4 h-chains (h = tid+256e,
// stride-256 so cur1 loads coalesce and nothing touches LDS in the t-loop).
// w2 (40 values/thread) lives in registers; per-t the 10 outputs are
// shuffle-reduced across the wave and combined across 4 waves via LDS.
// Replaces scan1+gemm2 and eliminates the 102 MB spk1 round-trip.
// ---------------------------------------------------------------------------
__global__ __launch_bounds__(256)
void lif1_gemm2_kernel(const float* __restrict__ cur1,   // [B, T, H] fp32
                       const float* __restrict__ w2,     // [O, H] fp32
                       const float* __restrict__ beta_p,
                       float* __restrict__ cur2)         // [B*T, O] fp32
{
  __shared__ float sRed[4][O_SZ];

  const int tid = threadIdx.x;
  const int b   = blockIdx.x;
  const float beta = beta_p[0];

  // w2 fragments -> registers (static indexing only; 40 VGPRs).
  float w2r[4][O_SZ];
  #pragma unroll
  for (int e = 0; e < 4; ++e) {
    const int h = tid + 256 * e;
    #pragma unroll
    for (int o = 0; o < O_SZ; ++o)
      w2r[e][o] = (h < H_SZ) ? w2[o * H_SZ + h] : 0.f;
  }

  const float* c = cur1 + (size_t)b * T_STEPS * H_SZ;

  float mem[4] = {0.f, 0.f, 0.f, 0.f};
  float spk[4] = {0.f, 0.f, 0.f, 0.f};

  // Prefetch t=0.
  float nxt[4];
  #pragma unroll
  for (int e = 0; e < 4; ++e) {
    const int h = tid + 256 * e;
    nxt[e] = (h < H_SZ) ? c[h] : 0.f;
  }

  for (int t = 0; t < T_STEPS; ++t) {
    float cu[4];
    #pragma unroll
    for (int e = 0; e < 4; ++e) cu[e] = nxt[e];

    // Prefetch t+1 (covers HBM latency under the reduce below).
    if (t + 1 < T_STEPS) {
      const float* cn = c + (size_t)(t + 1) * H_SZ;
      #pragma unroll
      for (int e = 0; e < 4; ++e) {
        const int h = tid + 256 * e;
        nxt[e] = (h < H_SZ) ? cn[h] : 0.f;
      }
    }

    // LIF update (snntorch Leaky, subtract reset, THR=1).
    #pragma unroll
    for (int e = 0; e < 4; ++e) {
      mem[e] = beta * mem[e] + cu[e] - spk[e];
      spk[e] = (mem[e] > 1.0f) ? 1.0f : 0.0f;
    }

    // cur2[t][o] = sum_h spk*w2 : per-thread 4 FMA, then wave shuffle-tree,
    // then cross-wave combine via LDS.
    #pragma unroll
    for (int o = 0; o < O_SZ; ++o) {
      float v = spk[0] * w2r[0][o] + spk[1] * w2r[1][o]
              + spk[2] * w2r[2][o] + spk[3] * w2r[3][o];
      #pragma unroll
      for (int off = 32; off > 0; off >>= 1) v += __shfl_down(v, off);
      if ((tid & 63) == 0) sRed[tid >> 6][o] = v;
    }
    __syncthreads();
    if (tid < O_SZ)
      cur2[((size_t)b * T_STEPS + t) * O_SZ + tid] =
          sRed[0][tid] + sRed[1][tid] + sRed[2][tid] + sRed[3][tid];
    __syncthreads();   // sRed reused next t
  }
}

// ---------------------------------------------------------------------------
// Phase 3: layer-2 scan + write outputs (fp32).
// ---------------------------------------------------------------------------
__global__ __launch_bounds__(256)
void scan2_kernel(const float* __restrict__ cur2,   // [B*T, O]
                  const float* __restrict__ b2,
                  const float* __restrict__ beta_p,
                  float* __restrict__ out)
{
  const int idx = blockIdx.x * 256 + threadIdx.x;
  if (idx >= B_SZ * O_SZ) return;
  const int b = idx / O_SZ;
  const int o = idx % O_SZ;
  const float beta = beta_p[0];
  const float bias = b2[o];
  float* spk_rec = out;
  float* mem_rec = out + (size_t)T_STEPS * B_SZ * O_SZ;
  float mem = 0.f, spk = 0.f;
  for (int t = 0; t < T_STEPS; ++t) {
    const float cur = cur2[((size_t)b * T_STEPS + t) * O_SZ + o] + bias;
    mem = beta * mem + cur - spk;
    spk = (mem > 1.0f) ? 1.0f : 0.0f;
    const size_t oi = ((size_t)t * B_SZ + b) * O_SZ + o;
    spk_rec[oi] = spk;
    mem_rec[oi] = mem;
  }
}

// ---------------------------------------------------------------------------
extern "C" void kernel_launch(void* const* d_in, const int* in_sizes, int n_in,
                              void* d_out, int out_size, void* d_ws, size_t ws_size,
                              hipStream_t stream)
{
  const float* data = (const float*)d_in[0]; // [B,T,2,34,34] -> [25600, 2312]
  const float* w1   = (const float*)d_in[1]; // [1000, 2312]
  const float* b1   = (const float*)d_in[2]; // [1000]
  const float* w2   = (const float*)d_in[3]; // [10, 1000]
  const float* b2   = (const float*)d_in[4]; // [10]
  const float* beta = (const float*)d_in[5]; // [1]
  float* out = (float*)d_out;                // 2 * [100,256,10] fp32

  // Workspace (~113 MB):
  //   wHi, wLo : f16 [1024, 2336]  = 4.78 MB each
  //   cur1     : fp32 [25600,1000] = 102.4 MB
  //   cur2     : fp32 [25600,10]   = 1.02 MB
  char* p = (char*)d_ws;
  auto take = [&](size_t n) { char* q = p; p += (n + 255) & ~(size_t)255; return q; };
  _Float16* wHi  = (_Float16*)take((size_t)W_ROWS * K_PAD * 2);
  _Float16* wLo  = (_Float16*)take((size_t)W_ROWS * K_PAD * 2);
  float*    cur1 = (float*)take((size_t)M_ROWS * H_SZ * 4);
  float*    cur2 = (float*)take((size_t)M_ROWS * O_SZ * 4);

  splitW_kernel<<<dim3(W_ROWS), 256, 0, stream>>>(w1, wHi, wLo);
  gemm1_fused<<<dim3(1600), 256, 0, stream>>>(data, wHi, wLo, b1, cur1);
  lif1_gemm2_kernel<<<dim3(B_SZ), 256, 0, stream>>>(cur1, w2, beta, cur2);
  scan2_kernel<<<dim3(10), 256, 0, stream>>>(cur2, b2, beta, out);
}

// Round 4
// 763.579 us; speedup vs baseline: 1.2356x; 1.2356x over previous
//
#include <hip/hip_runtime.h>
#include <hip/hip_bf16.h>
#include <stdint.h>

// Problem dims (hardcoded from reference):
// B=256, T=100, D=2*34*34=2312, H=1000, O=10.  ALL tensors fp32.
#define T_STEPS 100
#define B_SZ    256
#define D_IN    2312
#define H_SZ    1000
#define O_SZ    10
#define M_ROWS  (B_SZ * T_STEPS)   // 25600
#define K_PAD   2336               // 73 * 32 (W pre-split padded)
#define KT      73
#define W_ROWS  1024               // H padded to 1024 rows (rows >= 1000 zeroed)

// fp16 split scaling keeps lo-parts out of f16 subnormals.
// A*16 (|a|<6), W*64 (|w|<0.022).  Epilogue scale = 1/1024 (exact pow2).
#define A_SCALE   16.0f
#define W_SCALE   64.0f
#define INV_SCALE (1.0f / 1024.0f)

typedef __attribute__((ext_vector_type(4))) float     floatx4;
typedef __attribute__((ext_vector_type(8))) _Float16  halfx8;

#define ASYNC_COPY16(g, l)                                             \
  __builtin_amdgcn_global_load_lds(                                    \
      (const __attribute__((address_space(1))) void*)(g),              \
      (__attribute__((address_space(3))) void*)(l), 16, 0, 0)

// ---------------------------------------------------------------------------
// W pre-split: fp32 -> f16 hi/lo, scaled by 64, rows padded to K_PAD/W_ROWS.
// ---------------------------------------------------------------------------
__global__ __launch_bounds__(256)
void splitW_kernel(const float* __restrict__ W,    // [H_SZ, D_IN]
                   _Float16* __restrict__ wHi,     // [W_ROWS, K_PAD]
                   _Float16* __restrict__ wLo)
{
  const int r = blockIdx.x;
  const bool rvalid = (r < H_SZ);
  const float* w = W + (size_t)(rvalid ? r : 0) * D_IN;
  _Float16* ho = wHi + (size_t)r * K_PAD;
  _Float16* lo = wLo + (size_t)r * K_PAD;
  for (int c = threadIdx.x; c < K_PAD / 8; c += 256) {
    const int k0 = c * 8;
    const bool v = rvalid && (k0 + 8 <= D_IN);
    _Float16 h[8], l[8];
    #pragma unroll
    for (int e = 0; e < 8; ++e) {
      const float x = v ? w[k0 + e] * W_SCALE : 0.f;
      const _Float16 hb = (_Float16)x;
      h[e] = hb;
      l[e] = (_Float16)(x - (float)hb);
    }
    *reinterpret_cast<uint4*>(ho + k0) = *reinterpret_cast<const uint4*>(h);
    *reinterpret_cast<uint4*>(lo + k0) = *reinterpret_cast<const uint4*>(l);
  }
}

// ---------------------------------------------------------------------------
// Phase 1 (fused): cur1 = (A*16 fp32->f16split @ Wsplit) / 1024 + b1.
//
// Round-9: 256x256 tile, BK=32, 512 threads / 8 waves (2x4), wave-tile
// 128x64 (M_rep=8, N_rep=4).  Rationale: the 128x128 structure measured
// 790 TF effective = the documented m97-structure ceiling (MfmaUtil ~36%);
// its per-wave LDS-read:MFMA ratio (16 b128 : 48) makes the LDS pipe the
// floor.  128x64 wave tiles cut that to 24 : 96, making MFMA (931 cyc/SIMD
// /iter) > LDS (~1024 cyc/CU/iter) -- compute-dominated.
//
// Carried over verbatim from the verified round-8 kernel:
//  * staging map (thread owns rows r0=tid>>2 and r0+128, slot tid&3, XOR
//    chunk swizzle rho=(r0>>1)&3) -- note rho(r0)==rho(r0+128) since 128>>1
//    is a multiple of 4, so one ko serves both rows;
//  * counted-vmcnt pipeline: loop-top invariant outstanding vmem =
//    [W-DMA(kt) oldest 4][A-loads(kt+1) newest 4]; s_waitcnt vmcnt(4)
//    retires exactly W(kt); this iter's W(kt+1)/A(kt+2) fly across the
//    next barrier (T4: never drain to 0);
//  * per-element MFMA accumulation order (per kt: hh, lh, hl) -- numerics
//    bit-identical, absmax must stay 0.03125.
// LDS 128 KB (the verified 8-phase-template size) -> 1 block/CU, 8 waves
// = 2 waves/SIMD (same waves/SIMD as the 128x128 version had).
// ---------------------------------------------------------------------------
__global__ __launch_bounds__(512, 2)
void gemm1_fused(const float* __restrict__ A,       // [M_ROWS, D_IN] fp32
                 const _Float16* __restrict__ wHi,  // [W_ROWS, K_PAD]
                 const _Float16* __restrict__ wLo,
                 const float* __restrict__ b1,      // [H_SZ]
                 float* __restrict__ C)             // [M_ROWS, H_SZ]
{
  __shared__ _Float16 sAh[2][256 * 32];   // 16 KB per buffer
  __shared__ _Float16 sAl[2][256 * 32];
  __shared__ _Float16 sBh[2][256 * 32];
  __shared__ _Float16 sBl[2][256 * 32];   // 128 KB total -> 1 block/CU

  const int tid  = threadIdx.x;

  // XCD-aware remap (bijective: 400 = 8 XCDs x 50).  Consecutive l on one
  // XCD share an A slab (nt fastest) -> A re-reads hit that XCD's L2.
  const int id = blockIdx.x;             // 0..399, XCD = id & 7
  const int l  = (id & 7) * 50 + (id >> 3);
  const int mt = l >> 2;                 // 0..99
  const int nt = l & 3;                  // 0..3
  const int m0 = mt * 256;
  const int n0 = nt * 256;

  const int wid  = tid >> 6;             // 0..7
  const int lane = tid & 63;
  const int wm   = (wid & 1) * 128;      // wave tile 128x64
  const int wn   = (wid >> 1) * 64;
  const int quad = lane >> 4;
  const int l16  = lane & 15;

  floatx4 acc[8][4];
  #pragma unroll
  for (int i = 0; i < 8; ++i)
    #pragma unroll
    for (int jj = 0; jj < 4; ++jj)
      acc[i][jj] = floatx4{0.f, 0.f, 0.f, 0.f};

  // Staging map: thread tid owns rows r0=tid>>2 (0..127) and r1=r0+128,
  // LDS slot tid&3.  Slot s of row r holds global chunk s ^ rho(r).
  const int r0  = tid >> 2;
  const int r1  = r0 + 128;
  const int sl  = tid & 3;
  const int rho = (r0 >> 1) & 3;
  const int ko  = ((sl ^ rho) * 8);   // swizzled global chunk offset (elements)

  const float* gA0 = A + (size_t)(m0 + r0) * D_IN + ko;
  const float* gA1 = A + (size_t)(m0 + r1) * D_IN + ko;
  const _Float16* gBh0 = wHi + (size_t)(n0 + r0) * K_PAD + ko;
  const _Float16* gBh1 = wHi + (size_t)(n0 + r1) * K_PAD + ko;
  const _Float16* gBl0 = wLo + (size_t)(n0 + r0) * K_PAD + ko;
  const _Float16* gBl1 = wLo + (size_t)(n0 + r1) * K_PAD + ko;

  const int la0 = tid * 8;            // rows 0..127 region
  const int la1 = (tid + 512) * 8;    // rows 128..255 region

  // Fragment-read swizzle offset (elements); frag row bases are multiples
  // of 16 so rho(row) = (l16>>1)&3.
  const int fo = (quad ^ ((l16 >> 1) & 3)) * 8;

  // ---- Prologue.  Issue A(0) FIRST (retires first), then W(0) DMA.
  float a0[8], a1[8];
  *reinterpret_cast<float4*>(a0)     = *reinterpret_cast<const float4*>(gA0);
  *reinterpret_cast<float4*>(a0 + 4) = *reinterpret_cast<const float4*>(gA0 + 4);
  *reinterpret_cast<float4*>(a1)     = *reinterpret_cast<const float4*>(gA1);
  *reinterpret_cast<float4*>(a1 + 4) = *reinterpret_cast<const float4*>(gA1 + 4);

  ASYNC_COPY16(gBh0, &sBh[0][la0]);
  ASYNC_COPY16(gBh1, &sBh[0][la1]);
  ASYNC_COPY16(gBl0, &sBl[0][la0]);
  ASYNC_COPY16(gBl1, &sBl[0][la1]);

  // Split A(0) -> sA[0] (compiler waits the A(0) loads, leaves W(0) flying).
  {
    _Float16 h0[8], l0[8], h1[8], l1[8];
    #pragma unroll
    for (int e = 0; e < 8; ++e) {
      const float v0 = a0[e] * A_SCALE;
      const _Float16 hb0 = (_Float16)v0;
      h0[e] = hb0; l0[e] = (_Float16)(v0 - (float)hb0);
      const float v1 = a1[e] * A_SCALE;
      const _Float16 hb1 = (_Float16)v1;
      h1[e] = hb1; l1[e] = (_Float16)(v1 - (float)hb1);
    }
    *reinterpret_cast<uint4*>(&sAh[0][la0]) = *reinterpret_cast<const uint4*>(h0);
    *reinterpret_cast<uint4*>(&sAl[0][la0]) = *reinterpret_cast<const uint4*>(l0);
    *reinterpret_cast<uint4*>(&sAh[0][la1]) = *reinterpret_cast<const uint4*>(h1);
    *reinterpret_cast<uint4*>(&sAl[0][la1]) = *reinterpret_cast<const uint4*>(l1);
  }

  // A(1) into registers (in-bounds: 32 + ko + 8 <= 64 < D_IN).
  *reinterpret_cast<float4*>(a0)     = *reinterpret_cast<const float4*>(gA0 + 32);
  *reinterpret_cast<float4*>(a0 + 4) = *reinterpret_cast<const float4*>(gA0 + 36);
  *reinterpret_cast<float4*>(a1)     = *reinterpret_cast<const float4*>(gA1 + 32);
  *reinterpret_cast<float4*>(a1 + 4) = *reinterpret_cast<const float4*>(gA1 + 36);
  bool curValid = true;
  // Entering loop: outstanding = [W(0) x4 older][A(1) x4 newer].

  for (int kt = 0; kt < KT; ++kt) {
    const int p = kt & 1;

    // Counted barrier: retire W(kt) (fills [p]); keep A(kt+1) in flight.
    asm volatile("s_waitcnt vmcnt(4) lgkmcnt(0)" ::: "memory");
    __builtin_amdgcn_sched_barrier(0);
    __builtin_amdgcn_s_barrier();
    __builtin_amdgcn_sched_barrier(0);

    // ---- (1) B fragments of tile kt from [p] (8 x ds_read_b128).
    halfx8 bh[4], bl[4];
    #pragma unroll
    for (int jj = 0; jj < 4; ++jj) {
      const int row = (wn + jj * 16 + l16) * 32 + fo;
      bh[jj] = *reinterpret_cast<const halfx8*>(&sBh[p][row]);
      bl[jj] = *reinterpret_cast<const halfx8*>(&sBl[p][row]);
    }

    // ---- (2) stage tile kt+1 into [p^1]: split A(kt+1) -> ds_write,
    // then W-DMA(kt+1), then A-load(kt+2).  Maintains loop-top invariant.
    if (kt + 1 < KT) {
      _Float16 h0[8], l0[8], h1[8], l1[8];
      #pragma unroll
      for (int e = 0; e < 8; ++e) {
        const float v0 = curValid ? a0[e] * A_SCALE : 0.f;
        const _Float16 hb0 = (_Float16)v0;
        h0[e] = hb0; l0[e] = (_Float16)(v0 - (float)hb0);
        const float v1 = curValid ? a1[e] * A_SCALE : 0.f;
        const _Float16 hb1 = (_Float16)v1;
        h1[e] = hb1; l1[e] = (_Float16)(v1 - (float)hb1);
      }
      const int q = p ^ 1;
      *reinterpret_cast<uint4*>(&sAh[q][la0]) = *reinterpret_cast<const uint4*>(h0);
      *reinterpret_cast<uint4*>(&sAl[q][la0]) = *reinterpret_cast<const uint4*>(l0);
      *reinterpret_cast<uint4*>(&sAh[q][la1]) = *reinterpret_cast<const uint4*>(h1);
      *reinterpret_cast<uint4*>(&sAl[q][la1]) = *reinterpret_cast<const uint4*>(l1);

      const int kb = (kt + 1) * 32;
      ASYNC_COPY16(gBh0 + kb, &sBh[q][la0]);
      ASYNC_COPY16(gBh1 + kb, &sBh[q][la1]);
      ASYNC_COPY16(gBl0 + kb, &sBl[q][la0]);
      ASYNC_COPY16(gBl1 + kb, &sBl[q][la1]);

      // A(kt+2) regs -- ALWAYS issued (clamped) to keep the vmcnt invariant.
      const int kb2 = (kt + 2) * 32;
      const bool v = (kb2 + ko) < D_IN;      // chunk fully valid (D_IN%8==0)
      const int off = v ? kb2 : 0;
      *reinterpret_cast<float4*>(a0)     = *reinterpret_cast<const float4*>(gA0 + off);
      *reinterpret_cast<float4*>(a0 + 4) = *reinterpret_cast<const float4*>(gA0 + off + 4);
      *reinterpret_cast<float4*>(a1)     = *reinterpret_cast<const float4*>(gA1 + off);
      *reinterpret_cast<float4*>(a1 + 4) = *reinterpret_cast<const float4*>(gA1 + off + 4);
      curValid = v;
    }

    // ---- (3) per-i: A fragments (2 x ds_read_b128) + 12 MFMA.
    // Per-acc order per kt is hh, lh, hl -- identical accumulation chain
    // to all previous rounds (bit-exact).
    __builtin_amdgcn_s_setprio(1);
    #pragma unroll
    for (int i = 0; i < 8; ++i) {
      const int row = (wm + i * 16 + l16) * 32 + fo;
      const halfx8 ah = *reinterpret_cast<const halfx8*>(&sAh[p][row]);
      const halfx8 al = *reinterpret_cast<const halfx8*>(&sAl[p][row]);
      #pragma unroll
      for (int jj = 0; jj < 4; ++jj) {
        acc[i][jj] = __builtin_amdgcn_mfma_f32_16x16x32_f16(ah, bh[jj], acc[i][jj], 0, 0, 0);
        acc[i][jj] = __builtin_amdgcn_mfma_f32_16x16x32_f16(al, bh[jj], acc[i][jj], 0, 0, 0);
        acc[i][jj] = __builtin_amdgcn_mfma_f32_16x16x32_f16(ah, bl[jj], acc[i][jj], 0, 0, 0);
      }
    }
    __builtin_amdgcn_s_setprio(0);
  }

  // Epilogue: C/D layout col = lane&15, row = quad*4 + reg (m89/m91 verified).
  #pragma unroll
  for (int jj = 0; jj < 4; ++jj) {
    const int col = n0 + wn + jj * 16 + l16;
    if (col < H_SZ) {
      const float bias = b1[col];
      #pragma unroll
      for (int i = 0; i < 8; ++i) {
        const int row = m0 + wm + i * 16 + quad * 4;
        #pragma unroll
        for (int r = 0; r < 4; ++r)
          C[(size_t)(row + r) * H_SZ + col] = acc[i][jj][r] * INV_SCALE + bias;
      }
    }
  }
}

// ---------------------------------------------------------------------------
// Phase 2a: layer-1 LIF scan. One thread per (b,h) chain.
// (Round-2 tail restored: the round-3 scan+gemm fusion regressed the tail
//  331 -> 479 us -- 1 block/CU + 200 block barriers on the serial t-chain.)
// ---------------------------------------------------------------------------
__global__ __launch_bounds__(256)
void scan1_kernel(const float* __restrict__ cur1,     // [B, T, H] fp32
                  const float* __restrict__ beta_p,
                  __hip_bfloat16* __restrict__ spk1)  // [B, T, H] bf16 (0/1)
{
  const int h = blockIdx.x * 256 + threadIdx.x;
  const int b = blockIdx.y;
  if (h >= H_SZ) return;
  const float beta = beta_p[0];
  const float* c    = cur1 + (size_t)b * T_STEPS * H_SZ + h;
  __hip_bfloat16* s = spk1 + (size_t)b * T_STEPS * H_SZ + h;
  float mem = 0.f, spk = 0.f;
  #pragma unroll 4
  for (int t = 0; t < T_STEPS; ++t) {
    mem = beta * mem + c[(size_t)t * H_SZ] - spk;
    spk = (mem > 1.0f) ? 1.0f : 0.0f;
    s[(size_t)t * H_SZ] = __float2bfloat16(spk);
  }
}

// ---------------------------------------------------------------------------
// Phase 2b: cur2[m][o] = sum_h spk1[m][h] * w2[o][h].  Wave per row m.
// Spikes are exactly 0/1 -> accumulate w2 where spike!=0 (exact).
// ---------------------------------------------------------------------------
__global__ __launch_bounds__(256)
void gemm2_kernel(const __hip_bfloat16* __restrict__ spk1, // [M_ROWS, H]
                  const float* __restrict__ w2,            // [O, H] fp32
                  float* __restrict__ cur2)                // [M_ROWS, O]
{
  const int wid  = threadIdx.x >> 6;
  const int lane = threadIdx.x & 63;
  const int m    = blockIdx.x * 4 + wid;

  float acc[O_SZ];
  #pragma unroll
  for (int o = 0; o < O_SZ; ++o) acc[o] = 0.f;

  const __hip_bfloat16* row = spk1 + (size_t)m * H_SZ;
  #pragma unroll
  for (int it = 0; it < 16; ++it) {
    const int h = it * 64 + lane;
    if (h < H_SZ) {
      const float s = __bfloat162float(row[h]);
      if (s != 0.f) {
        #pragma unroll
        for (int o = 0; o < O_SZ; ++o)
          acc[o] += w2[o * H_SZ + h];
      }
    }
  }
  #pragma unroll
  for (int o = 0; o < O_SZ; ++o) {
    float v = acc[o];
    #pragma unroll
    for (int off = 32; off > 0; off >>= 1) v += __shfl_down(v, off);
    if (lane == 0) cur2[(size_t)m * O_SZ + o] = v;
  }
}

// ---------------------------------------------------------------------------
// Phase 2c: layer-2 scan + write outputs (fp32).
// ---------------------------------------------------------------------------
__global__ __launch_bounds__(256)
void scan2_kernel(const float* __restrict__ cur2,   // [B*T, O]
                  const float* __restrict__ b2,
                  const float* __restrict__ beta_p,
                  float* __restrict__ out)
{
  const int idx = blockIdx.x * 256 + threadIdx.x;
  if (idx >= B_SZ * O_SZ) return;
  const int b = idx / O_SZ;
  const int o = idx % O_SZ;
  const float beta = beta_p[0];
  const float bias = b2[o];
  float* spk_rec = out;
  float* mem_rec = out + (size_t)T_STEPS * B_SZ * O_SZ;
  float mem = 0.f, spk = 0.f;
  for (int t = 0; t < T_STEPS; ++t) {
    const float cur = cur2[((size_t)b * T_STEPS + t) * O_SZ + o] + bias;
    mem = beta * mem + cur - spk;
    spk = (mem > 1.0f) ? 1.0f : 0.0f;
    const size_t oi = ((size_t)t * B_SZ + b) * O_SZ + o;
    spk_rec[oi] = spk;
    mem_rec[oi] = mem;
  }
}

// ---------------------------------------------------------------------------
extern "C" void kernel_launch(void* const* d_in, const int* in_sizes, int n_in,
                              void* d_out, int out_size, void* d_ws, size_t ws_size,
                              hipStream_t stream)
{
  const float* data = (const float*)d_in[0]; // [B,T,2,34,34] -> [25600, 2312]
  const float* w1   = (const float*)d_in[1]; // [1000, 2312]
  const float* b1   = (const float*)d_in[2]; // [1000]
  const float* w2   = (const float*)d_in[3]; // [10, 1000]
  const float* b2   = (const float*)d_in[4]; // [10]
  const float* beta = (const float*)d_in[5]; // [1]
  float* out = (float*)d_out;                // 2 * [100,256,10] fp32

  // Workspace (~164 MB):
  //   wHi, wLo : f16 [1024, 2336]  = 4.78 MB each
  //   cur1     : fp32 [25600,1000] = 102.4 MB
  //   spk1     : bf16 [25600,1000] = 51.2 MB
  //   cur2     : fp32 [25600,10]   = 1.02 MB
  char* p = (char*)d_ws;
  auto take = [&](size_t n) { char* q = p; p += (n + 255) & ~(size_t)255; return q; };
  _Float16*       wHi  = (_Float16*)take((size_t)W_ROWS * K_PAD * 2);
  _Float16*       wLo  = (_Float16*)take((size_t)W_ROWS * K_PAD * 2);
  float*          cur1 = (float*)take((size_t)M_ROWS * H_SZ * 4);
  __hip_bfloat16* spk1 = (__hip_bfloat16*)take((size_t)M_ROWS * H_SZ * 2);
  float*          cur2 = (float*)take((size_t)M_ROWS * O_SZ * 4);

  splitW_kernel<<<dim3(W_ROWS), 256, 0, stream>>>(w1, wHi, wLo);
  gemm1_fused<<<dim3(400), 512, 0, stream>>>(data, wHi, wLo, b1, cur1);
  scan1_kernel<<<dim3(4, B_SZ), 256, 0, stream>>>(cur1, beta, spk1);
  gemm2_kernel<<<dim3(M_ROWS / 4), 256, 0, stream>>>(spk1, w2, cur2);
  scan2_kernel<<<dim3(10), 256, 0, stream>>>(cur2, b2, beta, out);
}

// Round 5
// 731.679 us; speedup vs baseline: 1.2895x; 1.0436x over previous
//
#include <hip/hip_runtime.h>
#include <hip/hip_bf16.h>
#include <stdint.h>

// Problem dims (hardcoded from reference):
// B=256, T=100, D=2*34*34=2312, H=1000, O=10.  ALL tensors fp32.
#define T_STEPS 100
#define B_SZ    256
#define D_IN    2312
#define H_SZ    1000
#define O_SZ    10
#define M_ROWS  (B_SZ * T_STEPS)   // 25600
#define K_PAD   2336               // 73 * 32 (W pre-split padded)
#define KT      73
#define W_ROWS  1024               // H padded to 1024 rows (rows >= 1000 zeroed)

// fp16 split scaling keeps lo-parts out of f16 subnormals.
// A*16 (|a|<6), W*64 (|w|<0.022).  Epilogue scale = 1/1024 (exact pow2).
#define A_SCALE   16.0f
#define W_SCALE   64.0f
#define INV_SCALE (1.0f / 1024.0f)

typedef __attribute__((ext_vector_type(4))) float     floatx4;
typedef __attribute__((ext_vector_type(8))) _Float16  halfx8;

#define ASYNC_COPY16(g, l)                                             \
  __builtin_amdgcn_global_load_lds(                                    \
      (const __attribute__((address_space(1))) void*)(g),              \
      (__attribute__((address_space(3))) void*)(l), 16, 0, 0)

// ---------------------------------------------------------------------------
// W pre-split: fp32 -> f16 hi/lo, scaled by 64, rows padded to K_PAD/W_ROWS.
// ---------------------------------------------------------------------------
__global__ __launch_bounds__(256)
void splitW_kernel(const float* __restrict__ W,    // [H_SZ, D_IN]
                   _Float16* __restrict__ wHi,     // [W_ROWS, K_PAD]
                   _Float16* __restrict__ wLo)
{
  const int r = blockIdx.x;
  const bool rvalid = (r < H_SZ);
  const float* w = W + (size_t)(rvalid ? r : 0) * D_IN;
  _Float16* ho = wHi + (size_t)r * K_PAD;
  _Float16* lo = wLo + (size_t)r * K_PAD;
  for (int c = threadIdx.x; c < K_PAD / 8; c += 256) {
    const int k0 = c * 8;
    const bool v = rvalid && (k0 + 8 <= D_IN);
    _Float16 h[8], l[8];
    #pragma unroll
    for (int e = 0; e < 8; ++e) {
      const float x = v ? w[k0 + e] * W_SCALE : 0.f;
      const _Float16 hb = (_Float16)x;
      h[e] = hb;
      l[e] = (_Float16)(x - (float)hb);
    }
    *reinterpret_cast<uint4*>(ho + k0) = *reinterpret_cast<const uint4*>(h);
    *reinterpret_cast<uint4*>(lo + k0) = *reinterpret_cast<const uint4*>(l);
  }
}

// ---------------------------------------------------------------------------
// Phase 1 (fused): cur1 = (A*16 fp32->f16split @ Wsplit) / 1024 + b1.
//
// 256x256 tile, BK=32, 512 threads / 8 waves (2x4), wave-tile 128x64.
// Round-10: within-iter phase interleave.  Cycle model (per CU-iter):
// MFMA floor ~3090 cyc, LDS pipe ~3000 cyc -- balanced; measured 7020
// cyc/iter because the phases ran SERIALLY (all 8 waves burst 24 LDS
// reads after the barrier with zero MFMA in flight, then the MFMA
// cluster ran with LDS near-idle; round-9 additionally had STAGE between
// the barrier and ALL MFMAs).  Fix: STAGE moves to the middle of the
// MFMA i-loop (after i=3), A(kt+2) global prefetch to the iter end.
// MFMA i=0..3 issues as soon as B+A0 frags land, overlapping the other
// waves' read bursts; STAGE's ds_writes overlap MFMA i=4..7.
//
// Counted-vmcnt invariant (unchanged from round-8/9, verified): at loop
// top outstanding vmem = [W-DMA(kt) oldest 4][A-loads(kt+1) newest 4];
// s_waitcnt vmcnt(4) retires exactly W(kt).  Intra-iter issue order is
// still split->ds_write->W-DMA->A-loads, all before the next barrier.
// Numerics bit-identical (same per-acc MFMA order hh,lh,hl per kt):
// absmax must stay exactly 0.03125.
// ---------------------------------------------------------------------------
__global__ __launch_bounds__(512, 2)
void gemm1_fused(const float* __restrict__ A,       // [M_ROWS, D_IN] fp32
                 const _Float16* __restrict__ wHi,  // [W_ROWS, K_PAD]
                 const _Float16* __restrict__ wLo,
                 const float* __restrict__ b1,      // [H_SZ]
                 float* __restrict__ C)             // [M_ROWS, H_SZ]
{
  __shared__ _Float16 sAh[2][256 * 32];   // 16 KB per buffer
  __shared__ _Float16 sAl[2][256 * 32];
  __shared__ _Float16 sBh[2][256 * 32];
  __shared__ _Float16 sBl[2][256 * 32];   // 128 KB total -> 1 block/CU

  const int tid  = threadIdx.x;

  // XCD-aware remap (bijective: 400 = 8 XCDs x 50).
  const int id = blockIdx.x;             // 0..399, XCD = id & 7
  const int l  = (id & 7) * 50 + (id >> 3);
  const int mt = l >> 2;                 // 0..99
  const int nt = l & 3;                  // 0..3
  const int m0 = mt * 256;
  const int n0 = nt * 256;

  const int wid  = tid >> 6;             // 0..7
  const int lane = tid & 63;
  const int wm   = (wid & 1) * 128;      // wave tile 128x64
  const int wn   = (wid >> 1) * 64;
  const int quad = lane >> 4;
  const int l16  = lane & 15;

  floatx4 acc[8][4];
  #pragma unroll
  for (int i = 0; i < 8; ++i)
    #pragma unroll
    for (int jj = 0; jj < 4; ++jj)
      acc[i][jj] = floatx4{0.f, 0.f, 0.f, 0.f};

  // Staging map: thread tid owns rows r0=tid>>2 (0..127) and r1=r0+128,
  // LDS slot tid&3.  Slot s of row r holds global chunk s ^ rho(r).
  const int r0  = tid >> 2;
  const int r1  = r0 + 128;
  const int sl  = tid & 3;
  const int rho = (r0 >> 1) & 3;
  const int ko  = ((sl ^ rho) * 8);   // swizzled global chunk offset (elements)

  const float* gA0 = A + (size_t)(m0 + r0) * D_IN + ko;
  const float* gA1 = A + (size_t)(m0 + r1) * D_IN + ko;
  const _Float16* gBh0 = wHi + (size_t)(n0 + r0) * K_PAD + ko;
  const _Float16* gBh1 = wHi + (size_t)(n0 + r1) * K_PAD + ko;
  const _Float16* gBl0 = wLo + (size_t)(n0 + r0) * K_PAD + ko;
  const _Float16* gBl1 = wLo + (size_t)(n0 + r1) * K_PAD + ko;

  const int la0 = tid * 8;            // rows 0..127 region
  const int la1 = (tid + 512) * 8;    // rows 128..255 region

  // Fragment-read swizzle offset (elements).
  const int fo = (quad ^ ((l16 >> 1) & 3)) * 8;

  // ---- Prologue.  Issue A(0) FIRST (retires first), then W(0) DMA.
  float a0[8], a1[8];
  *reinterpret_cast<float4*>(a0)     = *reinterpret_cast<const float4*>(gA0);
  *reinterpret_cast<float4*>(a0 + 4) = *reinterpret_cast<const float4*>(gA0 + 4);
  *reinterpret_cast<float4*>(a1)     = *reinterpret_cast<const float4*>(gA1);
  *reinterpret_cast<float4*>(a1 + 4) = *reinterpret_cast<const float4*>(gA1 + 4);

  ASYNC_COPY16(gBh0, &sBh[0][la0]);
  ASYNC_COPY16(gBh1, &sBh[0][la1]);
  ASYNC_COPY16(gBl0, &sBl[0][la0]);
  ASYNC_COPY16(gBl1, &sBl[0][la1]);

  // Split A(0) -> sA[0] (compiler waits the A(0) loads, leaves W(0) flying).
  {
    _Float16 h0[8], l0[8], h1[8], l1[8];
    #pragma unroll
    for (int e = 0; e < 8; ++e) {
      const float v0 = a0[e] * A_SCALE;
      const _Float16 hb0 = (_Float16)v0;
      h0[e] = hb0; l0[e] = (_Float16)(v0 - (float)hb0);
      const float v1 = a1[e] * A_SCALE;
      const _Float16 hb1 = (_Float16)v1;
      h1[e] = hb1; l1[e] = (_Float16)(v1 - (float)hb1);
    }
    *reinterpret_cast<uint4*>(&sAh[0][la0]) = *reinterpret_cast<const uint4*>(h0);
    *reinterpret_cast<uint4*>(&sAl[0][la0]) = *reinterpret_cast<const uint4*>(l0);
    *reinterpret_cast<uint4*>(&sAh[0][la1]) = *reinterpret_cast<const uint4*>(h1);
    *reinterpret_cast<uint4*>(&sAl[0][la1]) = *reinterpret_cast<const uint4*>(l1);
  }

  // A(1) into registers (in-bounds: 32 + ko + 8 <= 64 < D_IN).
  *reinterpret_cast<float4*>(a0)     = *reinterpret_cast<const float4*>(gA0 + 32);
  *reinterpret_cast<float4*>(a0 + 4) = *reinterpret_cast<const float4*>(gA0 + 36);
  *reinterpret_cast<float4*>(a1)     = *reinterpret_cast<const float4*>(gA1 + 32);
  *reinterpret_cast<float4*>(a1 + 4) = *reinterpret_cast<const float4*>(gA1 + 36);
  bool curValid = true;
  // Entering loop: outstanding = [W(0) x4 older][A(1) x4 newer].

  for (int kt = 0; kt < KT; ++kt) {
    const int p = kt & 1;

    // Counted barrier: retire W(kt) (fills [p]); keep A(kt+1) in flight.
    asm volatile("s_waitcnt vmcnt(4) lgkmcnt(0)" ::: "memory");
    __builtin_amdgcn_sched_barrier(0);
    __builtin_amdgcn_s_barrier();
    __builtin_amdgcn_sched_barrier(0);

    // ---- (1) B fragments of tile kt from [p] (8 x ds_read_b128).
    halfx8 bh[4], bl[4];
    #pragma unroll
    for (int jj = 0; jj < 4; ++jj) {
      const int row = (wn + jj * 16 + l16) * 32 + fo;
      bh[jj] = *reinterpret_cast<const halfx8*>(&sBh[p][row]);
      bl[jj] = *reinterpret_cast<const halfx8*>(&sBl[p][row]);
    }

    // ---- (2) MFMA i-loop with STAGE in the middle (after i=3).
    __builtin_amdgcn_s_setprio(1);
    #pragma unroll
    for (int i = 0; i < 8; ++i) {
      if (i == 4) {
        // STAGE tile kt+1 into [p^1] mid-cluster: split A(kt+1) ->
        // ds_write, then W-DMA(kt+1).  Overlaps MFMA i=4..7.
        __builtin_amdgcn_s_setprio(0);
        if (kt + 1 < KT) {
          _Float16 h0[8], l0[8], h1[8], l1[8];
          #pragma unroll
          for (int e = 0; e < 8; ++e) {
            const float v0 = curValid ? a0[e] * A_SCALE : 0.f;
            const _Float16 hb0 = (_Float16)v0;
            h0[e] = hb0; l0[e] = (_Float16)(v0 - (float)hb0);
            const float v1 = curValid ? a1[e] * A_SCALE : 0.f;
            const _Float16 hb1 = (_Float16)v1;
            h1[e] = hb1; l1[e] = (_Float16)(v1 - (float)hb1);
          }
          const int q = p ^ 1;
          *reinterpret_cast<uint4*>(&sAh[q][la0]) = *reinterpret_cast<const uint4*>(h0);
          *reinterpret_cast<uint4*>(&sAl[q][la0]) = *reinterpret_cast<const uint4*>(l0);
          *reinterpret_cast<uint4*>(&sAh[q][la1]) = *reinterpret_cast<const uint4*>(h1);
          *reinterpret_cast<uint4*>(&sAl[q][la1]) = *reinterpret_cast<const uint4*>(l1);

          const int kb = (kt + 1) * 32;
          ASYNC_COPY16(gBh0 + kb, &sBh[q][la0]);
          ASYNC_COPY16(gBh1 + kb, &sBh[q][la1]);
          ASYNC_COPY16(gBl0 + kb, &sBl[q][la0]);
          ASYNC_COPY16(gBl1 + kb, &sBl[q][la1]);
        }
        __builtin_amdgcn_s_setprio(1);
      }
      const int row = (wm + i * 16 + l16) * 32 + fo;
      const halfx8 ah = *reinterpret_cast<const halfx8*>(&sAh[p][row]);
      const halfx8 al = *reinterpret_cast<const halfx8*>(&sAl[p][row]);
      #pragma unroll
      for (int jj = 0; jj < 4; ++jj) {
        acc[i][jj] = __builtin_amdgcn_mfma_f32_16x16x32_f16(ah, bh[jj], acc[i][jj], 0, 0, 0);
        acc[i][jj] = __builtin_amdgcn_mfma_f32_16x16x32_f16(al, bh[jj], acc[i][jj], 0, 0, 0);
        acc[i][jj] = __builtin_amdgcn_mfma_f32_16x16x32_f16(ah, bl[jj], acc[i][jj], 0, 0, 0);
      }
    }
    __builtin_amdgcn_s_setprio(0);

    // ---- (3) A(kt+2) global prefetch at iter end (lands by next iter's
    // STAGE, half an iteration away).  ALWAYS 4 loads (clamped) to keep
    // the vmcnt invariant; issued after the W-DMAs above.
    if (kt + 1 < KT) {
      const int kb2 = (kt + 2) * 32;
      const bool v = (kb2 + ko) < D_IN;      // chunk fully valid (D_IN%8==0)
      const int off = v ? kb2 : 0;
      *reinterpret_cast<float4*>(a0)     = *reinterpret_cast<const float4*>(gA0 + off);
      *reinterpret_cast<float4*>(a0 + 4) = *reinterpret_cast<const float4*>(gA0 + off + 4);
      *reinterpret_cast<float4*>(a1)     = *reinterpret_cast<const float4*>(gA1 + off);
      *reinterpret_cast<float4*>(a1 + 4) = *reinterpret_cast<const float4*>(gA1 + off + 4);
      curValid = v;
    }
  }

  // Epilogue: C/D layout col = lane&15, row = quad*4 + reg (m89/m91 verified).
  #pragma unroll
  for (int jj = 0; jj < 4; ++jj) {
    const int col = n0 + wn + jj * 16 + l16;
    if (col < H_SZ) {
      const float bias = b1[col];
      #pragma unroll
      for (int i = 0; i < 8; ++i) {
        const int row = m0 + wm + i * 16 + quad * 4;
        #pragma unroll
        for (int r = 0; r < 4; ++r)
          C[(size_t)(row + r) * H_SZ + col] = acc[i][jj][r] * INV_SCALE + bias;
      }
    }
  }
}

// ---------------------------------------------------------------------------
// Phase 2a: layer-1 LIF scan -> bit-packed spikes.  One thread per (b,h)
// chain; wave ballots its 64 spike bools into one u64 per t (bit-exact:
// spikes are exactly 0/1).  Write traffic 51.2 MB -> 3.2 MB.
// ---------------------------------------------------------------------------
__global__ __launch_bounds__(256)
void scan1_kernel(const float* __restrict__ cur1,            // [B, T, H] fp32
                  const float* __restrict__ beta_p,
                  unsigned long long* __restrict__ spkbits)  // [B*T, 16]
{
  const int h = blockIdx.x * 256 + threadIdx.x;
  const int b = blockIdx.y;
  if (h >= H_SZ) return;
  const int g    = h >> 6;              // u64 group index (0..15)
  const int lane = threadIdx.x & 63;
  const float beta = beta_p[0];
  const float* c = cur1 + (size_t)b * T_STEPS * H_SZ + h;
  float mem = 0.f, spk = 0.f;
  #pragma unroll 4
  for (int t = 0; t < T_STEPS; ++t) {
    mem = beta * mem + c[(size_t)t * H_SZ] - spk;
    spk = (mem > 1.0f) ? 1.0f : 0.0f;
    const unsigned long long mask = __ballot(spk != 0.f);
    if (lane == 0)
      spkbits[((size_t)b * T_STEPS + t) * 16 + g] = mask;
  }
}

// ---------------------------------------------------------------------------
// Phase 2b: cur2[m][o] = sum_h spk1[m][h] * w2[o][h].  Wave per row m.
// Spikes come as 16 u64 bitmasks per row; branchless FMA with s in {0,1}
// (exact).  w2 (40 KB) is L1/L2-resident.
// ---------------------------------------------------------------------------
__global__ __launch_bounds__(256)
void gemm2_kernel(const unsigned long long* __restrict__ spkbits, // [M_ROWS,16]
                  const float* __restrict__ w2,                   // [O, H] fp32
                  float* __restrict__ cur2)                       // [M_ROWS, O]
{
  const int wid  = threadIdx.x >> 6;
  const int lane = threadIdx.x & 63;
  const int m    = blockIdx.x * 4 + wid;

  float acc[O_SZ];
  #pragma unroll
  for (int o = 0; o < O_SZ; ++o) acc[o] = 0.f;

  const unsigned long long* bits = spkbits + (size_t)m * 16;
  #pragma unroll
  for (int g = 0; g < 16; ++g) {
    const unsigned long long mask = bits[g];
    const float s = (float)((mask >> lane) & 1ull);
    const int h  = g * 64 + lane;
    const int hc = (h < H_SZ) ? h : (H_SZ - 1);   // clamp; s==0 there
    #pragma unroll
    for (int o = 0; o < O_SZ; ++o)
      acc[o] = fmaf(s, w2[o * H_SZ + hc], acc[o]);
  }
  #pragma unroll
  for (int o = 0; o < O_SZ; ++o) {
    float v = acc[o];
    #pragma unroll
    for (int off = 32; off > 0; off >>= 1) v += __shfl_down(v, off);
    if (lane == 0) cur2[(size_t)m * O_SZ + o] = v;
  }
}

// ---------------------------------------------------------------------------
// Phase 2c: layer-2 scan + write outputs (fp32).
// ---------------------------------------------------------------------------
__global__ __launch_bounds__(256)
void scan2_kernel(const float* __restrict__ cur2,   // [B*T, O]
                  const float* __restrict__ b2,
                  const float* __restrict__ beta_p,
                  float* __restrict__ out)
{
  const int idx = blockIdx.x * 256 + threadIdx.x;
  if (idx >= B_SZ * O_SZ) return;
  const int b = idx / O_SZ;
  const int o = idx % O_SZ;
  const float beta = beta_p[0];
  const float bias = b2[o];
  float* spk_rec = out;
  float* mem_rec = out + (size_t)T_STEPS * B_SZ * O_SZ;
  float mem = 0.f, spk = 0.f;
  for (int t = 0; t < T_STEPS; ++t) {
    const float cur = cur2[((size_t)b * T_STEPS + t) * O_SZ + o] + bias;
    mem = beta * mem + cur - spk;
    spk = (mem > 1.0f) ? 1.0f : 0.0f;
    const size_t oi = ((size_t)t * B_SZ + b) * O_SZ + o;
    spk_rec[oi] = spk;
    mem_rec[oi] = mem;
  }
}

// ---------------------------------------------------------------------------
extern "C" void kernel_launch(void* const* d_in, const int* in_sizes, int n_in,
                              void* d_out, int out_size, void* d_ws, size_t ws_size,
                              hipStream_t stream)
{
  const float* data = (const float*)d_in[0]; // [B,T,2,34,34] -> [25600, 2312]
  const float* w1   = (const float*)d_in[1]; // [1000, 2312]
  const float* b1   = (const float*)d_in[2]; // [1000]
  const float* w2   = (const float*)d_in[3]; // [10, 1000]
  const float* b2   = (const float*)d_in[4]; // [10]
  const float* beta = (const float*)d_in[5]; // [1]
  float* out = (float*)d_out;                // 2 * [100,256,10] fp32

  // Workspace (~117 MB):
  //   wHi, wLo : f16 [1024, 2336]  = 4.78 MB each
  //   cur1     : fp32 [25600,1000] = 102.4 MB
  //   spkbits  : u64  [25600,16]   = 3.28 MB
  //   cur2     : fp32 [25600,10]   = 1.02 MB
  char* p = (char*)d_ws;
  auto take = [&](size_t n) { char* q = p; p += (n + 255) & ~(size_t)255; return q; };
  _Float16*           wHi     = (_Float16*)take((size_t)W_ROWS * K_PAD * 2);
  _Float16*           wLo     = (_Float16*)take((size_t)W_ROWS * K_PAD * 2);
  float*              cur1    = (float*)take((size_t)M_ROWS * H_SZ * 4);
  unsigned long long* spkbits = (unsigned long long*)take((size_t)M_ROWS * 16 * 8);
  float*              cur2    = (float*)take((size_t)M_ROWS * O_SZ * 4);

  splitW_kernel<<<dim3(W_ROWS), 256, 0, stream>>>(w1, wHi, wLo);
  gemm1_fused<<<dim3(400), 512, 0, stream>>>(data, wHi, wLo, b1, cur1);
  scan1_kernel<<<dim3(4, B_SZ), 256, 0, stream>>>(cur1, beta, spkbits);
  gemm2_kernel<<<dim3(M_ROWS / 4), 256, 0, stream>>>(spkbits, w2, cur2);
  scan2_kernel<<<dim3(10), 256, 0, stream>>>(cur2, b2, beta, out);
}